// Round 5
// baseline (545.937 us; speedup 1.0000x reference)
//
#include <hip/hip_runtime.h>

#define B_DIM 2048
#define IN_DIM 1024
#define M_DIM 256
#define P_DIM 32896            // 256*257/2
#define RTP_B 43008            // elements per batch: row-tile-padded + 8/row skew
#define CRTP_BYTES (176160768) // 2048*43008*2
#define WB_BYTES   (67371008)  // 32896*1024*2

typedef __attribute__((ext_vector_type(8))) short short8;
typedef __attribute__((ext_vector_type(4))) float f32x4;

#define GLD16(gsrc, ldst) __builtin_amdgcn_global_load_lds(                    \
    (const __attribute__((address_space(1))) unsigned int*)(gsrc),             \
    (__attribute__((address_space(3))) unsigned int*)(ldst), 16, 0, 0)

__device__ __forceinline__ unsigned short f2bf(float f) {
    unsigned int u = __float_as_uint(f);
    u += 0x7FFFu + ((u >> 16) & 1u);          // RNE to bf16
    return (unsigned short)(u >> 16);
}
// base offset of row r in the skewed row-tile-padded layout
__device__ __forceinline__ int rtp_base(int r) {
    const int g = r >> 6;                      // row-tile 0..3
    return (g + 1) * 64 * ((g << 5) + (r & 63)) + (r << 3);
}

// ---------------- prep: zero ONLY the rtp pads ----------------
__global__ void pad_zero(unsigned short* __restrict__ Crtp) {
    const int r = threadIdx.x;                 // 256 rows
    const int b = blockIdx.x;                  // 2048 batches
    unsigned short* p = Crtp + (size_t)b * RTP_B + rtp_base(r) + r + 1;
    int n = 71 - (r & 63);
    if (((uintptr_t)p) & 2) { *p++ = 0; --n; } // align to 4B
    unsigned int* q = (unsigned int*)p;
    for (int i = 0; i < (n >> 1); ++i) q[i] = 0;
    if (n & 1) ((unsigned short*)q)[n - 1] = 0;
}

// ---------------- prep: X fp32 -> bf16 ----------------
__global__ void prep_x(const float* __restrict__ X, unsigned short* __restrict__ Xhi) {
    const int i = blockIdx.x * blockDim.x + threadIdx.x;       // one float4
    float4 v = reinterpret_cast<const float4*>(X)[i];
    ushort4 h;
    h.x = f2bf(v.x); h.y = f2bf(v.y); h.z = f2bf(v.z); h.w = f2bf(v.w);
    reinterpret_cast<ushort4*>(Xhi)[i] = h;
}

// ---------------- prep: W fp32 -> bf16 ----------------
__global__ void prep_w(const float* __restrict__ W, unsigned short* __restrict__ Wb) {
    const int i = blockIdx.x * blockDim.x + threadIdx.x;
    float4 v = reinterpret_cast<const float4*>(W)[i];
    ushort4 h;
    h.x = f2bf(v.x); h.y = f2bf(v.y); h.z = f2bf(v.z); h.w = f2bf(v.w);
    reinterpret_cast<ushort4*>(Wb)[i] = h;
}

// ---------------- Stage 1: C = Xhi @ Wb^T + bias, diag-ReLU, store rtp bf16 ----------
// BM=256, BN=128, BK=64. 512 threads = 8 waves (4M x 2N), wave tile 64x64.
// Triple-buffered LDS, prefetch depth 2, counted vmcnt(6), 1 barrier/iter, setprio.
// Grid 2080 = 8 XCDs x 260. XCD (assumed lin%8) = (rg = x&1, cg = x>>1):
//   rg owns 4 row-tiles (1024 rows, X-slice 2 MB -> L2-resident),
//   cg owns 65 col-panels streamed once; 4 consecutive blocks share one W panel.
__global__ __launch_bounds__(512) void gemm1_kernel(
    const unsigned short* __restrict__ Xhi,
    const unsigned short* __restrict__ Wb, const float* __restrict__ bias,
    unsigned short* __restrict__ Crtp)
{
    __shared__ unsigned short lds[3 * 24576];      // per buf: A 16384 el | B 8192 el

    const int lin = blockIdx.x;
    const int x   = lin & 7;                       // XCD (round-robin dispatch assumption)
    const int j   = lin >> 3;                      // 0..259 within XCD
    const int rtile = ((x & 1) << 2) + (j & 3);    // 0..7
    const int panel = (x >> 1) * 65 + (j >> 2);    // 0..259
    if (panel >= 257) return;
    const int row0 = rtile << 8;
    const int col0 = panel << 7;

    const int tid  = threadIdx.x;
    const int lane = tid & 63;
    const int wid  = tid >> 6;                     // 0..7
    const int wr   = wid >> 1;                     // 0..3
    const int wc   = wid & 1;                      // 0..1
    const int lr16 = lane & 15;
    const int kc   = lane >> 4;

    // staging: 48 x 1KB chunks per K-tile (A = chunks 0..31, B = 32..47);
    // wave stages chunks [6*wid, 6*wid+6). lane -> row lane>>3, 16B-chunk pre-XOR'd.
    const int srow = lane >> 3;
    const int sch  = (lane & 7) ^ srow;
    const unsigned short* gsrc[6];
    int loff[6];
#pragma unroll
    for (int i = 0; i < 6; ++i) {
        const int c = 6 * wid + i;
        if (c < 32) {
            gsrc[i] = Xhi + (size_t)(row0 + c * 8 + srow) * IN_DIM + (sch << 3);
            loff[i] = c * 512;
        } else {
            gsrc[i] = Wb + (size_t)(col0 + (c - 32) * 8 + srow) * IN_DIM + (sch << 3);
            loff[i] = 16384 + (c - 32) * 512;
        }
    }

#define STAGE(kt, bufo)                                                        \
    {                                                                          \
        _Pragma("unroll")                                                      \
        for (int i = 0; i < 6; ++i)                                            \
            GLD16(gsrc[i] + ((kt) << 6), &lds[(bufo) + loff[i]]);              \
    }

    f32x4 acc[4][4];
#pragma unroll
    for (int m = 0; m < 4; ++m)
#pragma unroll
        for (int n = 0; n < 4; ++n) acc[m][n] = (f32x4){0.f, 0.f, 0.f, 0.f};

    int o0 = 0, o1 = 24576, o2 = 49152;
    STAGE(0, o0);
    STAGE(1, o1);

    for (int it = 0; it < 16; ++it) {
        if (it < 15) asm volatile("s_waitcnt vmcnt(6)" ::: "memory");
        else         asm volatile("s_waitcnt vmcnt(0)" ::: "memory");
        __builtin_amdgcn_s_barrier();
        asm volatile("" ::: "memory");             // keep ds_reads below the barrier

        const int cb = o0;
        // ---- phase 0: k-half s=0 ----
        short8 av[4], bv[4];
#pragma unroll
        for (int m = 0; m < 4; ++m) {
            const int r = (wr << 6) + (m << 4) + lr16;
            av[m] = *reinterpret_cast<const short8*>(&lds[cb + r * 64 + (kc ^ (r & 7)) * 8]);
        }
#pragma unroll
        for (int n = 0; n < 4; ++n) {
            const int r = (wc << 6) + (n << 4) + lr16;
            bv[n] = *reinterpret_cast<const short8*>(&lds[cb + 16384 + r * 64 + (kc ^ (r & 7)) * 8]);
        }
        if (it < 14) STAGE(it + 2, o2);            // prefetch depth 2
        __builtin_amdgcn_s_setprio(1);
#pragma unroll
        for (int m = 0; m < 4; ++m)
#pragma unroll
            for (int n = 0; n < 4; ++n)
                acc[m][n] = __builtin_amdgcn_mfma_f32_16x16x32_bf16(av[m], bv[n], acc[m][n], 0, 0, 0);
        __builtin_amdgcn_s_setprio(0);

        // ---- phase 1: k-half s=1 ----
#pragma unroll
        for (int m = 0; m < 4; ++m) {
            const int r = (wr << 6) + (m << 4) + lr16;
            av[m] = *reinterpret_cast<const short8*>(&lds[cb + r * 64 + ((4 + kc) ^ (r & 7)) * 8]);
        }
#pragma unroll
        for (int n = 0; n < 4; ++n) {
            const int r = (wc << 6) + (n << 4) + lr16;
            bv[n] = *reinterpret_cast<const short8*>(&lds[cb + 16384 + r * 64 + ((4 + kc) ^ (r & 7)) * 8]);
        }
        __builtin_amdgcn_s_setprio(1);
#pragma unroll
        for (int m = 0; m < 4; ++m)
#pragma unroll
            for (int n = 0; n < 4; ++n)
                acc[m][n] = __builtin_amdgcn_mfma_f32_16x16x32_bf16(av[m], bv[n], acc[m][n], 0, 0, 0);
        __builtin_amdgcn_s_setprio(0);

        const int t = o0; o0 = o1; o1 = o2; o2 = t;   // rotate ring
    }
#undef STAGE

    // epilogue: D col = lane&15, row = (lane>>4)*4 + reg
#pragma unroll
    for (int n = 0; n < 4; ++n) {
        const int p = col0 + (wc << 6) + (n << 4) + lr16;     // packed tril index
        const float t = sqrtf((float)(8 * p + 1));
        const int rt = (int)((t - 1.0f) * 0.5f + 0.001f);     // tril row
        const int ct = p - ((rt * (rt + 1)) >> 1);            // tril col
        const int off = rtp_base(rt) + ct;
        const bool diag = (ct == rt);
        const float bvs = bias[p];
#pragma unroll
        for (int m = 0; m < 4; ++m) {
#pragma unroll
            for (int q = 0; q < 4; ++q) {
                const int brow = row0 + (wr << 6) + (m << 4) + (kc << 2) + q;
                float v = acc[m][n][q] + bvs;
                if (diag) v = fmaxf(v, 0.f);
                Crtp[(size_t)brow * RTP_B + off] = f2bf(v);
            }
        }
    }
}

// ---------------- Stage 2: O[b] = L_b @ L_b^T, LDS-free (direct global reads) ----------
// One block per batch, 4 waves, 4x4-balanced tile lists (k-cost 8/8/7/7). Per-batch
// working set 86 KB is L1/L2-hot; no staging barrier -> ~4 blocks/CU, full overlap
// of reads / MFMA / the 536 MB output write (the true floor, ~85 us).
__global__ __launch_bounds__(256) void syrk_kernel(
    const unsigned short* __restrict__ Crtp, float* __restrict__ O)
{
    const int tid  = threadIdx.x;
    const int lane = tid & 63;
    const int wid  = tid >> 6;
    const int b    = blockIdx.x;
    const unsigned short* Cb = Crtp + (size_t)b * RTP_B;

    const int lr16 = lane & 15;
    const int kc   = lane >> 4;
    float* Ob = O + (size_t)b * (M_DIM * M_DIM);

    const unsigned char LIST[4][5] = {
        {0x33, 0x22, 0x00, 0x00, 0x00},
        {0x23, 0x32, 0x01, 0x10, 0x00},
        {0x11, 0x12, 0x21, 0x02, 0x00},
        {0x13, 0x31, 0x03, 0x30, 0x20}};
    const int CNT[4] = {3, 4, 4, 5};
    const int cnt = CNT[wid];

    for (int tt = 0; tt < cnt; ++tt) {
        const int code = LIST[wid][tt];
        const int ti = code >> 4, tj = code & 15;

        int baseA[4], baseB[4];
#pragma unroll
        for (int m = 0; m < 4; ++m) {
            const int ia = (ti << 6) + (m << 4) + lr16;
            const int jb = (tj << 6) + (m << 4) + lr16;
            baseA[m] = rtp_base(ia) + (kc << 3);
            baseB[m] = rtp_base(jb) + (kc << 3);
        }
        f32x4 acc[4][4];
#pragma unroll
        for (int m = 0; m < 4; ++m)
#pragma unroll
            for (int n = 0; n < 4; ++n) acc[m][n] = (f32x4){0.f, 0.f, 0.f, 0.f};

        const int kmax = ti < tj ? ti : tj;
        for (int kt = 0; kt <= kmax; ++kt) {
#pragma unroll
            for (int s = 0; s < 2; ++s) {
                const int ko = (kt << 6) + (s << 5);
                short8 a[4], bb[4];
#pragma unroll
                for (int m = 0; m < 4; ++m)
                    a[m] = *reinterpret_cast<const short8*>(Cb + baseA[m] + ko);
#pragma unroll
                for (int n = 0; n < 4; ++n)
                    bb[n] = *reinterpret_cast<const short8*>(Cb + baseB[n] + ko);
#pragma unroll
                for (int m = 0; m < 4; ++m)
#pragma unroll
                    for (int n = 0; n < 4; ++n)
                        acc[m][n] = __builtin_amdgcn_mfma_f32_16x16x32_bf16(a[m], bb[n], acc[m][n], 0, 0, 0);
            }
        }
#pragma unroll
        for (int m = 0; m < 4; ++m) {
            const int i0 = (ti << 6) + (m << 4) + (kc << 2);
#pragma unroll
            for (int n = 0; n < 4; ++n) {
                const int j = (tj << 6) + (n << 4) + lr16;
#pragma unroll
                for (int q = 0; q < 4; ++q)
                    Ob[(size_t)(i0 + q) * M_DIM + j] = acc[m][n][q];
            }
        }
    }
}

extern "C" void kernel_launch(void* const* d_in, const int* in_sizes, int n_in,
                              void* d_out, int out_size, void* d_ws, size_t ws_size,
                              hipStream_t stream)
{
    (void)in_sizes; (void)n_in; (void)out_size; (void)ws_size;
    const float* x    = (const float*)d_in[0];
    const float* W    = (const float*)d_in[1];
    const float* bias = (const float*)d_in[2];
    float* O = (float*)d_out;

    char* ws = (char*)d_ws;
    unsigned short* Crtp = (unsigned short*)ws;
    unsigned short* Wb   = (unsigned short*)(ws + CRTP_BYTES);
    unsigned short* Xhi  = (unsigned short*)(ws + CRTP_BYTES + WB_BYTES);

    pad_zero<<<B_DIM, 256, 0, stream>>>(Crtp);
    prep_x<<<(B_DIM * IN_DIM / 4) / 256, 256, 0, stream>>>(x, Xhi);
    prep_w<<<(P_DIM * IN_DIM / 4) / 256, 256, 0, stream>>>(W, Wb);
    gemm1_kernel<<<dim3(2080), dim3(512), 0, stream>>>(Xhi, Wb, bias, Crtp);
    syrk_kernel<<<dim3(B_DIM), dim3(256), 0, stream>>>(Crtp, O);
}

// Round 6
// 402.945 us; speedup vs baseline: 1.3549x; 1.3549x over previous
//
#include <hip/hip_runtime.h>

#define B_DIM 2048
#define IN_DIM 1024
#define M_DIM 256
#define P_DIM 32896            // 256*257/2
#define RTP_B 40960            // elements per batch: row-tile padded, chunk-XOR swizzled
#define CRTP_BYTES (167772160) // 2048*40960*2
#define WB_BYTES   (67371008)  // 32896*1024*2

typedef __attribute__((ext_vector_type(8))) short short8;
typedef __attribute__((ext_vector_type(4))) float f32x4;

#define GLD16(gsrc, ldst) __builtin_amdgcn_global_load_lds(                    \
    (const __attribute__((address_space(1))) unsigned int*)(gsrc),             \
    (__attribute__((address_space(3))) unsigned int*)(ldst), 16, 0, 0)

__device__ __forceinline__ unsigned short f2bf(float f) {
    unsigned int u = __float_as_uint(f);
    u += 0x7FFFu + ((u >> 16) & 1u);          // RNE to bf16
    return (unsigned short)(u >> 16);
}
// base offset of row r: tile g padded to (g+1)*64 cols, no skew (rows 128B-aligned)
__device__ __forceinline__ int rtp0(int r) {
    const int g = r >> 6;
    return 2048 * g * (g + 1) + (r & 63) * ((g + 1) << 6);
}
// element (r,c) physical offset: 8-el chunk index XOR'd by (r&7) (within 8-chunk groups)
__device__ __forceinline__ int rtp_off(int r, int c) {
    return rtp0(r) + (((c >> 3) ^ (r & 7)) << 3) + (c & 7);
}

// ---------------- prep: zero ONLY the rtp pads (cols r+1 .. rowlen-1 of row r) -------
__global__ void pad_zero(unsigned short* __restrict__ Crtp) {
    const int r = threadIdx.x;                 // 256 rows
    const int b = blockIdx.x;                  // 2048 batches
    const int g = r >> 6;
    const int nch = (g + 1) << 3;              // chunks in this row
    const int xm = r & 7;
    unsigned short* base = Crtp + (size_t)b * RTP_B + rtp0(r);
    // partial chunk containing col r: cols r+1 .. (r|7)
    const int pc = (r >> 3) ^ xm;
    for (int c = r + 1; (c >> 3) == (r >> 3); ++c) base[(pc << 3) + (c & 7)] = 0;
    // full pad chunks
    const uint4 z = make_uint4(0u, 0u, 0u, 0u);
    for (int cc = (r >> 3) + 1; cc < nch; ++cc)
        *reinterpret_cast<uint4*>(&base[(cc ^ xm) << 3]) = z;
}

// ---------------- prep: X fp32 -> bf16 ----------------
__global__ void prep_x(const float* __restrict__ X, unsigned short* __restrict__ Xhi) {
    const int i = blockIdx.x * blockDim.x + threadIdx.x;       // one float4
    float4 v = reinterpret_cast<const float4*>(X)[i];
    ushort4 h;
    h.x = f2bf(v.x); h.y = f2bf(v.y); h.z = f2bf(v.z); h.w = f2bf(v.w);
    reinterpret_cast<ushort4*>(Xhi)[i] = h;
}

// ---------------- prep: W fp32 -> bf16 ----------------
__global__ void prep_w(const float* __restrict__ W, unsigned short* __restrict__ Wb) {
    const int i = blockIdx.x * blockDim.x + threadIdx.x;
    float4 v = reinterpret_cast<const float4*>(W)[i];
    ushort4 h;
    h.x = f2bf(v.x); h.y = f2bf(v.y); h.z = f2bf(v.z); h.w = f2bf(v.w);
    reinterpret_cast<ushort4*>(Wb)[i] = h;
}

// ---------------- Stage 1: C = Xhi @ Wb^T + bias, diag-ReLU, store rtp bf16 ----------
// BM=256, BN=128, BK=64. 512 threads = 8 waves (4M x 2N), wave tile 64x64.
// Triple-buffered LDS, prefetch depth 2, counted vmcnt(6), 1 barrier/iter, setprio.
// Grid 2080 = 8 XCDs x 260; per XCD: 4 row-tiles (2 MB X slice, L2-resident) x 65
// W panels streamed once (4 consecutive same-XCD blocks share each panel).
__global__ __launch_bounds__(512) void gemm1_kernel(
    const unsigned short* __restrict__ Xhi,
    const unsigned short* __restrict__ Wb, const float* __restrict__ bias,
    unsigned short* __restrict__ Crtp)
{
    __shared__ unsigned short lds[3 * 24576];      // per buf: A 16384 el | B 8192 el

    const int lin = blockIdx.x;
    const int x   = lin & 7;                       // XCD (round-robin dispatch)
    const int j   = lin >> 3;                      // 0..259 within XCD
    const int rtile = ((x & 1) << 2) + (j & 3);    // 0..7
    const int panel = (x >> 1) * 65 + (j >> 2);    // 0..259
    if (panel >= 257) return;
    const int row0 = rtile << 8;
    const int col0 = panel << 7;

    const int tid  = threadIdx.x;
    const int lane = tid & 63;
    const int wid  = tid >> 6;                     // 0..7
    const int wr   = wid >> 1;                     // 0..3
    const int wc   = wid & 1;                      // 0..1
    const int lr16 = lane & 15;
    const int kc   = lane >> 4;

    // staging: 48 x 1KB chunks per K-tile (A = chunks 0..31, B = 32..47);
    // wave stages chunks [6*wid, 6*wid+6). lane -> row lane>>3, 16B-chunk pre-XOR'd.
    const int srow = lane >> 3;
    const int sch  = (lane & 7) ^ srow;
    const unsigned short* gsrc[6];
    int loff[6];
#pragma unroll
    for (int i = 0; i < 6; ++i) {
        const int c = 6 * wid + i;
        if (c < 32) {
            gsrc[i] = Xhi + (size_t)(row0 + c * 8 + srow) * IN_DIM + (sch << 3);
            loff[i] = c * 512;
        } else {
            gsrc[i] = Wb + (size_t)(col0 + (c - 32) * 8 + srow) * IN_DIM + (sch << 3);
            loff[i] = 16384 + (c - 32) * 512;
        }
    }

#define STAGE(kt, bufo)                                                        \
    {                                                                          \
        _Pragma("unroll")                                                      \
        for (int i = 0; i < 6; ++i)                                            \
            GLD16(gsrc[i] + ((kt) << 6), &lds[(bufo) + loff[i]]);              \
    }

    f32x4 acc[4][4];
#pragma unroll
    for (int m = 0; m < 4; ++m)
#pragma unroll
        for (int n = 0; n < 4; ++n) acc[m][n] = (f32x4){0.f, 0.f, 0.f, 0.f};

    int o0 = 0, o1 = 24576, o2 = 49152;
    STAGE(0, o0);
    STAGE(1, o1);

    for (int it = 0; it < 16; ++it) {
        if (it < 15) asm volatile("s_waitcnt vmcnt(6)" ::: "memory");
        else         asm volatile("s_waitcnt vmcnt(0)" ::: "memory");
        __builtin_amdgcn_s_barrier();
        asm volatile("" ::: "memory");             // keep ds_reads below the barrier

        const int cb = o0;
        // ---- phase 0: k-half s=0 ----
        short8 av[4], bv[4];
#pragma unroll
        for (int m = 0; m < 4; ++m) {
            const int r = (wr << 6) + (m << 4) + lr16;
            av[m] = *reinterpret_cast<const short8*>(&lds[cb + r * 64 + (kc ^ (r & 7)) * 8]);
        }
#pragma unroll
        for (int n = 0; n < 4; ++n) {
            const int r = (wc << 6) + (n << 4) + lr16;
            bv[n] = *reinterpret_cast<const short8*>(&lds[cb + 16384 + r * 64 + (kc ^ (r & 7)) * 8]);
        }
        if (it < 14) STAGE(it + 2, o2);            // prefetch depth 2
        __builtin_amdgcn_s_setprio(1);
#pragma unroll
        for (int m = 0; m < 4; ++m)
#pragma unroll
            for (int n = 0; n < 4; ++n)
                acc[m][n] = __builtin_amdgcn_mfma_f32_16x16x32_bf16(av[m], bv[n], acc[m][n], 0, 0, 0);
        __builtin_amdgcn_s_setprio(0);

        // ---- phase 1: k-half s=1 ----
#pragma unroll
        for (int m = 0; m < 4; ++m) {
            const int r = (wr << 6) + (m << 4) + lr16;
            av[m] = *reinterpret_cast<const short8*>(&lds[cb + r * 64 + ((4 + kc) ^ (r & 7)) * 8]);
        }
#pragma unroll
        for (int n = 0; n < 4; ++n) {
            const int r = (wc << 6) + (n << 4) + lr16;
            bv[n] = *reinterpret_cast<const short8*>(&lds[cb + 16384 + r * 64 + ((4 + kc) ^ (r & 7)) * 8]);
        }
        __builtin_amdgcn_s_setprio(1);
#pragma unroll
        for (int m = 0; m < 4; ++m)
#pragma unroll
            for (int n = 0; n < 4; ++n)
                acc[m][n] = __builtin_amdgcn_mfma_f32_16x16x32_bf16(av[m], bv[n], acc[m][n], 0, 0, 0);
        __builtin_amdgcn_s_setprio(0);

        const int t = o0; o0 = o1; o1 = o2; o2 = t;   // rotate ring
    }
#undef STAGE

    // epilogue: D col = lane&15, row = (lane>>4)*4 + reg
#pragma unroll
    for (int n = 0; n < 4; ++n) {
        const int p = col0 + (wc << 6) + (n << 4) + lr16;     // packed tril index
        const float t = sqrtf((float)(8 * p + 1));
        const int rt = (int)((t - 1.0f) * 0.5f + 0.001f);     // tril row
        const int ct = p - ((rt * (rt + 1)) >> 1);            // tril col
        const int off = rtp_off(rt, ct);                      // swizzled position
        const bool diag = (ct == rt);
        const float bvs = bias[p];
#pragma unroll
        for (int m = 0; m < 4; ++m) {
#pragma unroll
            for (int q = 0; q < 4; ++q) {
                const int brow = row0 + (wr << 6) + (m << 4) + (kc << 2) + q;
                float v = acc[m][n][q] + bvs;
                if (diag) v = fmaxf(v, 0.f);
                Crtp[(size_t)brow * RTP_B + off] = f2bf(v);
            }
        }
    }
}

// ---------------- Stage 2: O[b] = L_b @ L_b^T, LDS-staged (80 KB -> 2 blocks/CU) ------
// One block per batch, 4 waves, balanced tile lists (k-cost 8/8/7/7). Reads use the
// chunk-XOR swizzle (2-way banks = free); pads are zero => maskless MFMA.
__global__ __launch_bounds__(256) void syrk_kernel(
    const unsigned short* __restrict__ Crtp, float* __restrict__ O)
{
    __shared__ unsigned short Lt[RTP_B];       // 81920 B exactly -> 2 blocks/CU
    const int tid  = threadIdx.x;
    const int lane = tid & 63;
    const int wid  = tid >> 6;
    const int b    = blockIdx.x;
    const unsigned short* Cb = Crtp + (size_t)b * RTP_B;

    // linear stage: 80 x 1KiB global_load_lds (layout already swizzled by writer)
#pragma unroll
    for (int i = 0; i < 20; ++i) {
        const int g = wid * 20 + i;
        GLD16(Cb + g * 512 + (lane << 3), &Lt[g * 512]);
    }
    __syncthreads();

    const int lr16 = lane & 15;
    const int kc   = lane >> 4;
    float* Ob = O + (size_t)b * (M_DIM * M_DIM);

    const unsigned char LIST[4][5] = {
        {0x33, 0x22, 0x00, 0x00, 0x00},
        {0x23, 0x32, 0x01, 0x10, 0x00},
        {0x11, 0x12, 0x21, 0x02, 0x00},
        {0x13, 0x31, 0x03, 0x30, 0x20}};
    const int CNT[4] = {3, 4, 4, 5};
    const int cnt = CNT[wid];

    for (int tt = 0; tt < cnt; ++tt) {
        const int code = LIST[wid][tt];
        const int ti = code >> 4, tj = code & 15;

        int baseA[4], xA[4], baseB[4], xB[4];
#pragma unroll
        for (int m = 0; m < 4; ++m) {
            const int ia = (ti << 6) + (m << 4) + lr16;
            const int jb = (tj << 6) + (m << 4) + lr16;
            baseA[m] = rtp0(ia); xA[m] = ia & 7;
            baseB[m] = rtp0(jb); xB[m] = jb & 7;
        }
        f32x4 acc[4][4];
#pragma unroll
        for (int m = 0; m < 4; ++m)
#pragma unroll
            for (int n = 0; n < 4; ++n) acc[m][n] = (f32x4){0.f, 0.f, 0.f, 0.f};

        const int kmax = ti < tj ? ti : tj;
        for (int kt = 0; kt <= kmax; ++kt) {
#pragma unroll
            for (int s = 0; s < 2; ++s) {
                const int cidx = (kt << 3) + (s << 2) + kc;   // 8-el chunk index
                short8 a[4], bb[4];
#pragma unroll
                for (int m = 0; m < 4; ++m)
                    a[m] = *reinterpret_cast<const short8*>(&Lt[baseA[m] + ((cidx ^ xA[m]) << 3)]);
#pragma unroll
                for (int n = 0; n < 4; ++n)
                    bb[n] = *reinterpret_cast<const short8*>(&Lt[baseB[n] + ((cidx ^ xB[n]) << 3)]);
#pragma unroll
                for (int m = 0; m < 4; ++m)
#pragma unroll
                    for (int n = 0; n < 4; ++n)
                        acc[m][n] = __builtin_amdgcn_mfma_f32_16x16x32_bf16(a[m], bb[n], acc[m][n], 0, 0, 0);
            }
        }
#pragma unroll
        for (int m = 0; m < 4; ++m) {
            const int i0 = (ti << 6) + (m << 4) + (kc << 2);
#pragma unroll
            for (int n = 0; n < 4; ++n) {
                const int j = (tj << 6) + (n << 4) + lr16;
#pragma unroll
                for (int q = 0; q < 4; ++q)
                    __builtin_nontemporal_store(acc[m][n][q], &Ob[(size_t)(i0 + q) * M_DIM + j]);
            }
        }
    }
}

extern "C" void kernel_launch(void* const* d_in, const int* in_sizes, int n_in,
                              void* d_out, int out_size, void* d_ws, size_t ws_size,
                              hipStream_t stream)
{
    (void)in_sizes; (void)n_in; (void)out_size; (void)ws_size;
    const float* x    = (const float*)d_in[0];
    const float* W    = (const float*)d_in[1];
    const float* bias = (const float*)d_in[2];
    float* O = (float*)d_out;

    char* ws = (char*)d_ws;
    unsigned short* Crtp = (unsigned short*)ws;
    unsigned short* Wb   = (unsigned short*)(ws + CRTP_BYTES);
    unsigned short* Xhi  = (unsigned short*)(ws + CRTP_BYTES + WB_BYTES);

    pad_zero<<<B_DIM, 256, 0, stream>>>(Crtp);
    prep_x<<<(B_DIM * IN_DIM / 4) / 256, 256, 0, stream>>>(x, Xhi);
    prep_w<<<(P_DIM * IN_DIM / 4) / 256, 256, 0, stream>>>(W, Wb);
    gemm1_kernel<<<dim3(2080), dim3(512), 0, stream>>>(Xhi, Wb, bias, Crtp);
    syrk_kernel<<<dim3(B_DIM), dim3(256), 0, stream>>>(Crtp, O);
}